// Round 20
// baseline (111.878 us; speedup 1.0000x reference)
//
#include <hip/hip_runtime.h>
#include <hip/hip_fp16.h>

#define NBC 14
#define NAC 45
#define KF  52
#define RHO 0.05f
#define TT  4096
#define BB  64
#define CHC 64           // outputs per chain
#define WU  44           // warmup steps
#define NPAIR 32         // chunk pairs per batch
#define NTW (WU + CHC)   // 108 steps per chain
#define SPAN (WU + 2*CHC)// 172: xf range covers both chains
#define XPAD 176         // xf row stride (halfs), mult of 4
#define LOG2E 1.44269504f
#define XF_BYTES ((size_t)BB * NBC * TT * 2)

typedef float f2 __attribute__((ext_vector_type(2)));
typedef int   i2v __attribute__((ext_vector_type(2)));

__device__ __forceinline__ __half2 bch(unsigned u) { return __builtin_bit_cast(__half2, u); }
__device__ __forceinline__ unsigned bcu(__half2 h) { return __builtin_bit_cast(unsigned, h); }
__device__ __forceinline__ __half2 pk2(float lo, float hi) {
  return __floats2half2_rn(lo, hi);
}
// DPP row-rotate by J within 16-lane rows (pure VALU; rotates packed (A,B) pair)
template<int J>
__device__ __forceinline__ __half2 rot2(__half2 v) {
  return __builtin_bit_cast(__half2, __builtin_amdgcn_update_dpp(
      0, __builtin_bit_cast(int, v), 0x120 + J, 0xF, 0xF, true));
}
__device__ __forceinline__ __half2 xsum16h(__half2 v) {
#if __has_builtin(__builtin_amdgcn_permlane16_swap)
  i2v r = __builtin_amdgcn_permlane16_swap((int)bcu(v), (int)bcu(v), false, false);
  return __hadd2(bch((unsigned)r[0]), bch((unsigned)r[1]));
#else
  return __hadd2(v, bch((unsigned)__builtin_amdgcn_ds_swizzle((int)bcu(v), (16 << 10) | 0x1f)));
#endif
}
__device__ __forceinline__ __half2 xsum32h(__half2 v) {
#if __has_builtin(__builtin_amdgcn_permlane32_swap)
  i2v r = __builtin_amdgcn_permlane32_swap((int)bcu(v), (int)bcu(v), false, false);
  return __hadd2(bch((unsigned)r[0]), bch((unsigned)r[1]));
#else
  return __hadd2(v, bch((unsigned)__shfl_xor((int)bcu(v), 32)));
#endif
}
__device__ __forceinline__ float exp2_f(float x) {
#if __has_builtin(__builtin_amdgcn_exp2f)
  return __builtin_amdgcn_exp2f(x);
#else
  return exp2f(x);
#endif
}
__device__ __forceinline__ float sigm(float m) {   // m = -z*log2e
  return __fdividef(1.f, 1.f + exp2_f(m));
}

// ---------------- conv pre-pass: xf[b][c][t] for all t ----------------
__global__ __launch_bounds__(256)
void conv_kernel(const float* __restrict__ x, const float* __restrict__ bck,
                 __half* __restrict__ xfg) {
  __shared__ float xs[256 + KF];
  const int tid  = threadIdx.x;
  const int b    = blockIdx.x >> 4;
  const int t0   = (blockIdx.x & 15) << 8;
  for (int i = tid; i < 256 + KF - 1; i += 256) {
    int gt = t0 - (KF - 1) + i;
    xs[i] = (gt >= 0) ? x[b * TT + gt] : 0.f;
  }
  __syncthreads();
  float acc[NBC];
#pragma unroll
  for (int c = 0; c < NBC; ++c) acc[c] = 0.f;
#pragma unroll 4
  for (int k = 0; k < KF; ++k) {
    float xv = xs[tid + k];
#pragma unroll
    for (int c = 0; c < NBC; ++c) acc[c] = fmaf(bck[c * KF + k], xv, acc[c]);
  }
#pragma unroll
  for (int c = 0; c < NBC; ++c)
    xfg[((size_t)b * NBC + c) * TT + t0 + tid] = __float2half(acc[c]);
}

// LDS pool (bytes):
//  [0,    4928)  xf fp16 [NBC][XPAD]
//  [4928, 5824)  x slice f32 [224]  (in-kernel conv fallback only)
#define POOL_BYTES 5824

template<bool PRECONV>
__global__ __launch_bounds__(64)
void bcn_kernel(const float* __restrict__ x,
                const float* __restrict__ bck,
                const float* __restrict__ lss,
                const float* __restrict__ soff,
                const float* __restrict__ lbaw,
                const float* __restrict__ ltr,
                const float* __restrict__ ltd,
                const float* __restrict__ lass,
                const float* __restrict__ asoff,
                const float* __restrict__ labw,
                const float* __restrict__ oscale,
                const __half* __restrict__ xfg,
                float* __restrict__ out)
{
  __shared__ __align__(16) char pool[POOL_BYTES];
  __half* xf_lds = (__half*)pool;                    // [NBC][XPAD]
  float*  x_lds  = (float*)(pool + 4928);            // conv fallback only

  const int lid   = threadIdx.x;
  const int c16   = lid & 15;
  const int q     = lid >> 4;
  // NaN quarantine: out-of-role lanes (c16>=NBC) must read FINITE xf values,
  // since their rel enters rotation gathers (0 * NaN = NaN would propagate).
  const int crow  = (c16 < NBC) ? c16 : 0;
  const int blk   = blockIdx.x;
  const int b     = blk >> 5;            // batch
  const int p     = blk & 31;            // chunk pair
  const int t0A   = p * (2 * CHC);
  const int t_begin = t0A - WU;

  // DPP row_ror direction probe: rot<j> delivers lane srcl(j) = (c16 - delta*j) & 15
  const int probe = __builtin_amdgcn_update_dpp(0, c16, 0x121, 0xF, 0xF, true);
  const int delta = (c16 - probe) & 15;

  if constexpr (PRECONV) {
    const __half* src = xfg + (size_t)b * NBC * TT;
    if (p == 0) {
      for (int e = lid; e < NBC * SPAN; e += 64) {
        int c = e / SPAN, i = e - c * SPAN;
        int gt = t_begin + i; if (gt < 0) gt = 0;   // chain-A warm garbage, reset later
        xf_lds[c * XPAD + i] = src[(size_t)c * TT + gt];
      }
    } else {
      for (int c = 0; c < NBC; ++c) {
        if (lid < SPAN / 4) {
          uint2 v = *(const uint2*)(src + (size_t)c * TT + t_begin + 4 * lid);
          *(uint2*)&xf_lds[c * XPAD + 4 * lid] = v;
        }
      }
    }
  } else {
    for (int i = lid; i < SPAN + KF - 1; i += 64) {
      int gt = t_begin - (KF - 1) + i;
      x_lds[i] = (gt >= 0) ? x[b * TT + gt] : 0.f;
    }
    __syncthreads();
    for (int ib = 0; ib < 3; ++ib) {
      int tau = lid + (ib << 6);
      if (tau < SPAN) {
        float acc[NBC];
#pragma unroll
        for (int c = 0; c < NBC; ++c) acc[c] = 0.f;
#pragma unroll 4
        for (int k = 0; k < KF; ++k) {
          float xv = x_lds[tau + k];
#pragma unroll
          for (int c = 0; c < NBC; ++c) acc[c] = fmaf(bck[c * KF + k], xv, acc[c]);
        }
#pragma unroll
        for (int c = 0; c < NBC; ++c) xf_lds[c * XPAD + tau] = __float2half(acc[c]);
      }
    }
    __syncthreads();
  }

  // ---- per-lane parameters ----
  float slope2 = 0.f, soff2 = 0.f, osc_c = 0.f;
  f2 poolA; poolA.x = 1.f; poolA.y = 1.f;   // (BCN pool, LNR pool), chain A
  f2 poolB; poolB.x = 1.f; poolB.y = 1.f;
  f2 SA; SA.x = 0.f; SA.y = 0.f;            // (S1,S2) chain A
  f2 SB; SB.x = 0.f; SB.y = 0.f;
  f2 rv2, cn2; rv2.x = rv2.y = cn2.x = cn2.y = 0.f;
  float Adrv2 = 0.f, Boff2 = 0.f;
  __half2 wfbh[16];   // fb rotation weights (w,w): j -> -exp(labw[c16][16q+srcl(j)])
  __half2 wuh[16];    // u  rotation weights (w,w): j -> exp(lbaw[lid][srcl(j)])
  f2 yst[8], fst[8], lst[8];                // register output staging (8 steps)
  unsigned acst[8];

#pragma unroll
  for (int j = 0; j < 16; ++j) { wfbh[j] = pk2(0.f, 0.f); wuh[j] = pk2(0.f, 0.f); }

  if (c16 < NBC) {
    float sl = expf(lss[c16]);
    slope2 = sl * LOG2E;
    soff2  = soff[c16] * sl * LOG2E;
    osc_c  = oscale[c16];
    for (int j = 0; j < 16; ++j) {
      int srcl = (c16 - delta * j) & 15;
      int a = 16 * q + srcl;
      if (a < NAC) { float w = -expf(labw[c16 * NAC + a]); wfbh[j] = pk2(w, w); }
    }
  }
  if (lid < NAC) {
    float tr = expf(ltr[lid]);
    float td = expf(ltd[lid]);
    float a1 = 1.f / td;
    float gg = (td + tr) / (td * tr);
    rv2.x = expf(-a1 * 0.015625f);  rv2.y = expf(-gg * 0.015625f);
    cn2.x = expf(-a1 * 0.003125f);  cn2.y = expf(-gg * 0.003125f);
    float nrm = 0.f;
    for (int k = 0; k < KF; ++k) {
      float kt = 0.8f - (float)k * 0.015625f;
      float d = expf(-a1 * kt) - expf(-gg * kt);
      nrm = fmaf(d, d, nrm);
    }
    float inorm  = 1.f / sqrtf(nrm);
    float aslope = expf(lass[lid]);
    Adrv2 = aslope * inorm * LOG2E;
    Boff2 = aslope * asoff[lid] * LOG2E;
    for (int j = 0; j < 16; ++j) {
      int srcl = (c16 - delta * j) & 15;
      if (srcl < NBC) { float w = expf(lbaw[lid * NBC + srcl]); wuh[j] = pk2(w, w); }
    }
  }

  float* yb  = out;
  float* fbp = out + (size_t)BB * TT * NBC;
  float* acp = out + 2 * (size_t)BB * TT * NBC;
  float* ylp = out + 2 * (size_t)BB * TT * NBC + (size_t)BB * TT * NAC;

  __syncthreads();

  // ---- one dual-chain step: zero LDS/DS ops, all gathers on VALU ----
  auto step = [&](int slot, float xfA, float xfB, bool emit)
      __attribute__((always_inline)) {
    // AC sigmoids (all lanes; lanes>=45 have S=0 -> ac=0.5 against zero weights)
    float mzA = fmaf(-Adrv2, SA.x - SA.y, Boff2);
    float mzB = fmaf(-Adrv2, SB.x - SB.y, Boff2);
    float acA = sigm(mzA);
    float acB = sigm(mzB);
    __half2 ach = pk2(acA, acB);

    // fb[c16]: own-row partial via 15 DPP rotations + 16 pk_fma, then permlane sums
    __half2 g0 = __hmul2(wfbh[0], ach);
    __half2 g1 = __hmul2(wfbh[1], rot2<1>(ach));
    g0 = __hfma2(wfbh[2],  rot2<2>(ach),  g0);
    g1 = __hfma2(wfbh[3],  rot2<3>(ach),  g1);
    g0 = __hfma2(wfbh[4],  rot2<4>(ach),  g0);
    g1 = __hfma2(wfbh[5],  rot2<5>(ach),  g1);
    g0 = __hfma2(wfbh[6],  rot2<6>(ach),  g0);
    g1 = __hfma2(wfbh[7],  rot2<7>(ach),  g1);
    g0 = __hfma2(wfbh[8],  rot2<8>(ach),  g0);
    g1 = __hfma2(wfbh[9],  rot2<9>(ach),  g1);
    g0 = __hfma2(wfbh[10], rot2<10>(ach), g0);
    g1 = __hfma2(wfbh[11], rot2<11>(ach), g1);
    g0 = __hfma2(wfbh[12], rot2<12>(ach), g0);
    g1 = __hfma2(wfbh[13], rot2<13>(ach), g1);
    g0 = __hfma2(wfbh[14], rot2<14>(ach), g0);
    g1 = __hfma2(wfbh[15], rot2<15>(ach), g1);
    __half2 gs = xsum32h(xsum16h(__hadd2(g0, g1)));
    float fbA = __low2float(gs), fbB = __high2float(gs);

    // BCN + LNR sigmoids, both chains (no role-split: every row replicates)
    float mlA = fmaf(-slope2, xfA, soff2);
    float mpA = fmaf(-slope2, fbA, mlA);
    float mlB = fmaf(-slope2, xfB, soff2);
    float mpB = fmaf(-slope2, fbB, mlB);
    f2 pvA, pvB;
    pvA.x = sigm(mpA);  pvA.y = sigm(mlA);
    pvB.x = sigm(mpB);  pvB.y = sigm(mlB);
    f2 p2A = poolA * (1.f - RHO) + RHO;
    f2 p2B = poolB * (1.f - RHO) + RHO;
    f2 relA = pvA * p2A, relB = pvB * p2B;
    poolA = p2A - relA;  poolB = p2B - relB;
    __half2 relh = pk2(relA.x, relB.x);       // BCN releases, row-replicated (finite)

    if (emit) {
      f2 t1; t1.x = osc_c * relA.x; t1.y = osc_c * relB.x; yst[slot] = t1;
      f2 t2; t2.x = fbA;            t2.y = fbB;            fst[slot] = t2;
      f2 t3; t3.x = osc_c * relA.y; t3.y = osc_c * relB.y; lst[slot] = t3;
      acst[slot] = bcu(ach);
    }

    // u[lid]: within-row gather via 15 DPP rotations + 16 pk_fma (no cross-row)
    __half2 h0 = __hmul2(wuh[0], relh);
    __half2 h1 = __hmul2(wuh[1], rot2<1>(relh));
    h0 = __hfma2(wuh[2],  rot2<2>(relh),  h0);
    h1 = __hfma2(wuh[3],  rot2<3>(relh),  h1);
    h0 = __hfma2(wuh[4],  rot2<4>(relh),  h0);
    h1 = __hfma2(wuh[5],  rot2<5>(relh),  h1);
    h0 = __hfma2(wuh[6],  rot2<6>(relh),  h0);
    h1 = __hfma2(wuh[7],  rot2<7>(relh),  h1);
    h0 = __hfma2(wuh[8],  rot2<8>(relh),  h0);
    h1 = __hfma2(wuh[9],  rot2<9>(relh),  h1);
    h0 = __hfma2(wuh[10], rot2<10>(relh), h0);
    h1 = __hfma2(wuh[11], rot2<11>(relh), h1);
    h0 = __hfma2(wuh[12], rot2<12>(relh), h0);
    h1 = __hfma2(wuh[13], rot2<13>(relh), h1);
    h0 = __hfma2(wuh[14], rot2<14>(relh), h0);
    h1 = __hfma2(wuh[15], rot2<15>(relh), h1);
    __half2 uh = __hadd2(h0, h1);

    // infinite-history exponential states (rv2=cn2=0 for lanes>=45 -> S stays 0)
    SA = SA * rv2 + cn2 * __low2float(uh);
    SB = SB * rv2 + cn2 * __high2float(uh);
  };

  auto group = [&](int s4, int slotbase, bool emit) __attribute__((always_inline)) {
    uint2 xa = *(const uint2*)&xf_lds[crow * XPAD + s4];
    uint2 xb = *(const uint2*)&xf_lds[crow * XPAD + s4 + CHC];
    __half2 xA01 = bch(xa.x), xA23 = bch(xa.y);
    __half2 xB01 = bch(xb.x), xB23 = bch(xb.y);
    step(slotbase + 0, __low2float(xA01),  __low2float(xB01),  emit);
    step(slotbase + 1, __high2float(xA01), __high2float(xB01), emit);
    step(slotbase + 2, __low2float(xA23),  __low2float(xB23),  emit);
    step(slotbase + 3, __high2float(xA23), __high2float(xB23), emit);
  };

  // ---- warm phase ----
  for (int s4 = 0; s4 < WU; s4 += 4) group(s4, 0, false);

  // chunk-0 exact start: reset chain A state (true history is empty)
  if (p == 0) {
    SA.x = 0.f; SA.y = 0.f;
    poolA.x = 1.f; poolA.y = 1.f;
  }

  // ---- emit phase: 8 steps per flush ----
  for (int s8 = WU; s8 < NTW; s8 += 8) {
    group(s8, 0, true);
    group(s8 + 4, 4, true);

    int tg = t0A + (s8 - WU);
    size_t base = (size_t)b * TT + tg;
    if (lid < NBC) {                       // q=0 lanes: y_bcn + fb
      size_t ob = base * NBC + lid;
#pragma unroll
      for (int sl = 0; sl < 8; ++sl) {
        yb [ob + sl * NBC]                     = yst[sl].x;
        yb [ob + (size_t)CHC * NBC + sl * NBC] = yst[sl].y;
        fbp[ob + sl * NBC]                     = fst[sl].x;
        fbp[ob + (size_t)CHC * NBC + sl * NBC] = fst[sl].y;
      }
    } else if (lid >= 16 && lid < 16 + NBC) {  // q=1 lanes (replicated): y_lnr
      size_t ob = base * NBC + (lid - 16);
#pragma unroll
      for (int sl = 0; sl < 8; ++sl) {
        ylp[ob + sl * NBC]                     = lst[sl].x;
        ylp[ob + (size_t)CHC * NBC + sl * NBC] = lst[sl].y;
      }
    }
    if (lid < NAC) {
      size_t oa = base * NAC + lid;
#pragma unroll
      for (int sl = 0; sl < 8; ++sl) {
        __half2 h = bch(acst[sl]);
        acp[oa + sl * NAC]                     = __low2float(h);
        acp[oa + (size_t)CHC * NAC + sl * NAC] = __high2float(h);
      }
    }
  }
}

extern "C" void kernel_launch(void* const* d_in, const int* in_sizes, int n_in,
                              void* d_out, int out_size, void* d_ws, size_t ws_size,
                              hipStream_t stream) {
  (void)in_sizes; (void)n_in; (void)out_size;
  const float* x    = (const float*)d_in[0];
  const float* bck  = (const float*)d_in[1];
  if (ws_size >= XF_BYTES) {
    __half* xfg = (__half*)d_ws;
    conv_kernel<<<dim3(BB * 16), dim3(256), 0, stream>>>(x, bck, xfg);
    bcn_kernel<true><<<dim3(BB * NPAIR), dim3(64), 0, stream>>>(
        x, bck, (const float*)d_in[2], (const float*)d_in[3], (const float*)d_in[4],
        (const float*)d_in[5], (const float*)d_in[6], (const float*)d_in[7],
        (const float*)d_in[8], (const float*)d_in[9], (const float*)d_in[10],
        xfg, (float*)d_out);
  } else {
    bcn_kernel<false><<<dim3(BB * NPAIR), dim3(64), 0, stream>>>(
        x, bck, (const float*)d_in[2], (const float*)d_in[3], (const float*)d_in[4],
        (const float*)d_in[5], (const float*)d_in[6], (const float*)d_in[7],
        (const float*)d_in[8], (const float*)d_in[9], (const float*)d_in[10],
        (const __half*)nullptr, (float*)d_out);
  }
}

// Round 21
// 103.525 us; speedup vs baseline: 1.0807x; 1.0807x over previous
//
#include <hip/hip_runtime.h>
#include <hip/hip_fp16.h>

#define NBC 14
#define NAC 45
#define KF  52
#define RHO 0.05f
#define TT  4096
#define BB  64
#define CHC 64           // outputs per chain
#define WU  44           // warmup steps
#define NPAIR 32         // chunk pairs per batch
#define NTW (WU + CHC)   // 108 steps per chain
#define SPAN (WU + 2*CHC)// 172: xf range covers both chains
#define XPAD 176         // xf row stride (halfs), mult of 4
#define LOG2E 1.44269504f
#define XF_BYTES ((size_t)BB * NBC * TT * 2)

typedef float f2 __attribute__((ext_vector_type(2)));
typedef int   i2v __attribute__((ext_vector_type(2)));

__device__ __forceinline__ __half2 bch(unsigned u) { return __builtin_bit_cast(__half2, u); }
__device__ __forceinline__ unsigned bcu(__half2 h) { return __builtin_bit_cast(unsigned, h); }
__device__ __forceinline__ __half2 pk2(float lo, float hi) {
  return __floats2half2_rn(lo, hi);
}
// DPP row-rotate by J within 16-lane rows (pure VALU; moves packed u32)
template<int J>
__device__ __forceinline__ __half2 rotu(unsigned v) {
  return __builtin_bit_cast(__half2, __builtin_amdgcn_update_dpp(
      0, (int)v, 0x120 + J, 0xF, 0xF, true));
}
__device__ __forceinline__ __half2 xsum16h(__half2 v) {
#if __has_builtin(__builtin_amdgcn_permlane16_swap)
  i2v r = __builtin_amdgcn_permlane16_swap((int)bcu(v), (int)bcu(v), false, false);
  return __hadd2(bch((unsigned)r[0]), bch((unsigned)r[1]));
#else
  return __hadd2(v, bch((unsigned)__builtin_amdgcn_ds_swizzle((int)bcu(v), (16 << 10) | 0x1f)));
#endif
}
__device__ __forceinline__ __half2 xsum32h(__half2 v) {
#if __has_builtin(__builtin_amdgcn_permlane32_swap)
  i2v r = __builtin_amdgcn_permlane32_swap((int)bcu(v), (int)bcu(v), false, false);
  return __hadd2(bch((unsigned)r[0]), bch((unsigned)r[1]));
#else
  return __hadd2(v, bch((unsigned)__shfl_xor((int)bcu(v), 32)));
#endif
}
__device__ __forceinline__ float exp2_f(float x) {
#if __has_builtin(__builtin_amdgcn_exp2f)
  return __builtin_amdgcn_exp2f(x);
#else
  return exp2f(x);
#endif
}
__device__ __forceinline__ float sigm(float m) {   // m = -z*log2e
  return __fdividef(1.f, 1.f + exp2_f(m));
}

// ---------------- conv pre-pass: xf[b][c][t] for all t ----------------
__global__ __launch_bounds__(256)
void conv_kernel(const float* __restrict__ x, const float* __restrict__ bck,
                 __half* __restrict__ xfg) {
  __shared__ float xs[256 + KF];
  const int tid  = threadIdx.x;
  const int b    = blockIdx.x >> 4;
  const int t0   = (blockIdx.x & 15) << 8;
  for (int i = tid; i < 256 + KF - 1; i += 256) {
    int gt = t0 - (KF - 1) + i;
    xs[i] = (gt >= 0) ? x[b * TT + gt] : 0.f;
  }
  __syncthreads();
  float acc[NBC];
#pragma unroll
  for (int c = 0; c < NBC; ++c) acc[c] = 0.f;
#pragma unroll 4
  for (int k = 0; k < KF; ++k) {
    float xv = xs[tid + k];
#pragma unroll
    for (int c = 0; c < NBC; ++c) acc[c] = fmaf(bck[c * KF + k], xv, acc[c]);
  }
#pragma unroll
  for (int c = 0; c < NBC; ++c)
    xfg[((size_t)b * NBC + c) * TT + t0 + tid] = __float2half(acc[c]);
}

// LDS pool (bytes):
//  [0,    4928)  xf fp16 [NBC][XPAD]
//  [4928, 5184)  acr u32 [64]   (entries 45..63 stay zero; 16B aligned)
//  [5184, 5248)  relr u32 [16]  (entries 14,15 stay zero)
//  [5248, 6144)  x slice f32 [224]  (in-kernel conv fallback only)
#define POOL_BYTES 6144

template<bool PRECONV>
__global__ __launch_bounds__(64)
void bcn_kernel(const float* __restrict__ x,
                const float* __restrict__ bck,
                const float* __restrict__ lss,
                const float* __restrict__ soff,
                const float* __restrict__ lbaw,
                const float* __restrict__ ltr,
                const float* __restrict__ ltd,
                const float* __restrict__ lass,
                const float* __restrict__ asoff,
                const float* __restrict__ labw,
                const float* __restrict__ oscale,
                const __half* __restrict__ xfg,
                float* __restrict__ out)
{
  __shared__ __align__(16) char pool[POOL_BYTES];
  __half*   xf_lds = (__half*)pool;                    // [NBC][XPAD]
  unsigned* acr    = (unsigned*)(pool + 4928);         // [64]
  unsigned* relr   = (unsigned*)(pool + 5184);         // [16]
  float*    x_lds  = (float*)(pool + 5248);            // conv fallback only

  const int lid   = threadIdx.x;
  const int c16   = lid & 15;
  const int q     = lid >> 4;
  const int crow  = (c16 < NBC) ? c16 : 0;  // NaN quarantine for xf reads
  const float rowm = (q & 1) ? 0.f : 1.f;   // rows 0,2: BCN; rows 1,3: LNR
  const int j0    = c16 & 3;                // own chunk index within row
  const int blk   = blockIdx.x;
  const int b     = blk >> 5;            // batch
  const int p     = blk & 31;            // chunk pair
  const int t0A   = p * (2 * CHC);
  const int t_begin = t0A - WU;

  // DPP row_ror direction probe: rot<J> gives lane srcl(J) = (c16 - delta*J) & 15
  const int probe = __builtin_amdgcn_update_dpp(0, c16, 0x121, 0xF, 0xF, true);
  const int delta = (c16 - probe) & 15;

  if constexpr (PRECONV) {
    const __half* src = xfg + (size_t)b * NBC * TT;
    if (p == 0) {
      for (int e = lid; e < NBC * SPAN; e += 64) {
        int c = e / SPAN, i = e - c * SPAN;
        int gt = t_begin + i; if (gt < 0) gt = 0;   // chain-A warm garbage, reset later
        xf_lds[c * XPAD + i] = src[(size_t)c * TT + gt];
      }
    } else {
      for (int c = 0; c < NBC; ++c) {
        if (lid < SPAN / 4) {
          uint2 v = *(const uint2*)(src + (size_t)c * TT + t_begin + 4 * lid);
          *(uint2*)&xf_lds[c * XPAD + 4 * lid] = v;
        }
      }
    }
  } else {
    for (int i = lid; i < SPAN + KF - 1; i += 64) {
      int gt = t_begin - (KF - 1) + i;
      x_lds[i] = (gt >= 0) ? x[b * TT + gt] : 0.f;
    }
    __syncthreads();
    for (int ib = 0; ib < 3; ++ib) {
      int tau = lid + (ib << 6);
      if (tau < SPAN) {
        float acc[NBC];
#pragma unroll
        for (int c = 0; c < NBC; ++c) acc[c] = 0.f;
#pragma unroll 4
        for (int k = 0; k < KF; ++k) {
          float xv = x_lds[tau + k];
#pragma unroll
          for (int c = 0; c < NBC; ++c) acc[c] = fmaf(bck[c * KF + k], xv, acc[c]);
        }
#pragma unroll
        for (int c = 0; c < NBC; ++c) xf_lds[c * XPAD + tau] = __float2half(acc[c]);
      }
    }
    __syncthreads();
  }

  // ---- zero acr + relr (quarantine padding stays zero forever) ----
  if (lid < 64) acr[lid] = 0u;
  if (lid < 16) relr[lid] = 0u;

  // ---- per-lane parameters ----
  float slope2 = 0.f, soff2 = 0.f, osc_c = 0.f;
  f2 poolP; poolP.x = 1.f; poolP.y = 1.f;   // role pool (chain A, chain B)
  f2 SA; SA.x = 0.f; SA.y = 0.f;
  f2 SB; SB.x = 0.f; SB.y = 0.f;
  f2 rv2, cn2; rv2.x = rv2.y = cn2.x = cn2.y = 0.f;
  float Adrv2 = 0.f, Boff2 = 0.f;
  // chunk-rotation weights: [r*4+i] -> weight for element i of chunk ((c16-delta*r)&3)
  __half2 wfb4[16];
  __half2 wu4[16];
  f2 yst[8], fst[8];                        // register output staging (8 steps)
  unsigned acst[8];

#pragma unroll
  for (int j = 0; j < 16; ++j) { wfb4[j] = pk2(0.f, 0.f); wu4[j] = pk2(0.f, 0.f); }

  if (c16 < NBC) {
    float sl = expf(lss[c16]);
    slope2 = sl * LOG2E;
    soff2  = soff[c16] * sl * LOG2E;
    osc_c  = oscale[c16];
    for (int r = 0; r < 4; ++r) {
      int chunk = (c16 - delta * r) & 3;
      for (int i = 0; i < 4; ++i) {
        int a = 16 * q + 4 * chunk + i;
        if (a < NAC) { float w = -expf(labw[c16 * NAC + a]); wfb4[r * 4 + i] = pk2(w, w); }
      }
    }
  }
  if (lid < NAC) {
    float tr = expf(ltr[lid]);
    float td = expf(ltd[lid]);
    float a1 = 1.f / td;
    float gg = (td + tr) / (td * tr);
    rv2.x = expf(-a1 * 0.015625f);  rv2.y = expf(-gg * 0.015625f);
    cn2.x = expf(-a1 * 0.003125f);  cn2.y = expf(-gg * 0.003125f);
    float nrm = 0.f;
    for (int k = 0; k < KF; ++k) {
      float kt = 0.8f - (float)k * 0.015625f;
      float d = expf(-a1 * kt) - expf(-gg * kt);
      nrm = fmaf(d, d, nrm);
    }
    float inorm  = 1.f / sqrtf(nrm);
    float aslope = expf(lass[lid]);
    Adrv2 = aslope * inorm * LOG2E;
    Boff2 = aslope * asoff[lid] * LOG2E;
    for (int r = 0; r < 4; ++r) {
      int chunk = (c16 - delta * r) & 3;
      for (int i = 0; i < 4; ++i) {
        int c = 4 * chunk + i;
        if (c < NBC) { float w = expf(lbaw[lid * NBC + c]); wu4[r * 4 + i] = pk2(w, w); }
      }
    }
  }

  float* yb  = out;
  float* fbp = out + (size_t)BB * TT * NBC;
  float* acp = out + 2 * (size_t)BB * TT * NBC;
  float* ylp = out + 2 * (size_t)BB * TT * NBC + (size_t)BB * TT * NAC;

  __syncthreads();

  // ---- one dual-chain step: 1 b128 + 12 DPP per gather (DS pipe offload) ----
  auto step = [&](int slot, float xfA, float xfB, bool emit)
      __attribute__((always_inline)) {
    float mzA = fmaf(-Adrv2, SA.x - SA.y, Boff2);
    float mzB = fmaf(-Adrv2, SB.x - SB.y, Boff2);
    float acA = sigm(mzA);
    float acB = sigm(mzB);
    __half2 ach = pk2(acA, acB);
    if (lid < NAC) acr[lid] = bcu(ach);

    // fb: own chunk via 1 broadcast b128, other 3 chunks via DPP rotations
    uint4 av = *(const uint4*)(acr + (q << 4) + (j0 << 2));
    __half2 g0 = __hmul2(wfb4[0],  bch(av.x));
    __half2 g1 = __hmul2(wfb4[1],  bch(av.y));
    g0 = __hfma2(wfb4[2],  bch(av.z),    g0);
    g1 = __hfma2(wfb4[3],  bch(av.w),    g1);
    g0 = __hfma2(wfb4[4],  rotu<1>(av.x), g0);
    g1 = __hfma2(wfb4[5],  rotu<1>(av.y), g1);
    g0 = __hfma2(wfb4[6],  rotu<1>(av.z), g0);
    g1 = __hfma2(wfb4[7],  rotu<1>(av.w), g1);
    g0 = __hfma2(wfb4[8],  rotu<2>(av.x), g0);
    g1 = __hfma2(wfb4[9],  rotu<2>(av.y), g1);
    g0 = __hfma2(wfb4[10], rotu<2>(av.z), g0);
    g1 = __hfma2(wfb4[11], rotu<2>(av.w), g1);
    g0 = __hfma2(wfb4[12], rotu<3>(av.x), g0);
    g1 = __hfma2(wfb4[13], rotu<3>(av.y), g1);
    g0 = __hfma2(wfb4[14], rotu<3>(av.z), g0);
    g1 = __hfma2(wfb4[15], rotu<3>(av.w), g1);
    __half2 gs = xsum32h(xsum16h(__hadd2(g0, g1)));
    float fbA = __low2float(gs), fbB = __high2float(gs);

    // role-fused sigmoid: rows 0,2 see fb (BCN), rows 1,3 see 0 (LNR)
    float mA = fmaf(-slope2, fmaf(rowm, fbA, xfA), soff2);
    float mB = fmaf(-slope2, fmaf(rowm, fbB, xfB), soff2);
    f2 pv;
    pv.x = sigm(mA);
    pv.y = sigm(mB);
    f2 p2 = poolP * (1.f - RHO) + RHO;
    f2 relP = pv * p2;
    poolP = p2 - relP;
    if (lid < NBC) relr[lid] = bcu(pk2(relP.x, relP.y));   // row0 = BCN rel
    if (emit) {
      yst[slot] = relP * osc_c;            // row0: y_bcn; row1: y_lnr
      f2 t; t.x = fbA; t.y = fbB; fst[slot] = t;
      acst[slot] = bcu(ach);
    }

    // u: same chunk-rotation scheme on relr (16 u32, all rows read same)
    uint4 rv_ = *(const uint4*)(relr + (j0 << 2));
    __half2 h0 = __hmul2(wu4[0],  bch(rv_.x));
    __half2 h1 = __hmul2(wu4[1],  bch(rv_.y));
    h0 = __hfma2(wu4[2],  bch(rv_.z),     h0);
    h1 = __hfma2(wu4[3],  bch(rv_.w),     h1);
    h0 = __hfma2(wu4[4],  rotu<1>(rv_.x), h0);
    h1 = __hfma2(wu4[5],  rotu<1>(rv_.y), h1);
    h0 = __hfma2(wu4[6],  rotu<1>(rv_.z), h0);
    h1 = __hfma2(wu4[7],  rotu<1>(rv_.w), h1);
    h0 = __hfma2(wu4[8],  rotu<2>(rv_.x), h0);
    h1 = __hfma2(wu4[9],  rotu<2>(rv_.y), h1);
    h0 = __hfma2(wu4[10], rotu<2>(rv_.z), h0);
    h1 = __hfma2(wu4[11], rotu<2>(rv_.w), h1);
    h0 = __hfma2(wu4[12], rotu<3>(rv_.x), h0);
    h1 = __hfma2(wu4[13], rotu<3>(rv_.y), h1);
    h0 = __hfma2(wu4[14], rotu<3>(rv_.z), h0);
    h1 = __hfma2(wu4[15], rotu<3>(rv_.w), h1);
    __half2 uh = __hadd2(h0, h1);
    // infinite-history exponential states (rv2=cn2=0 for lanes>=45 -> S stays 0)
    SA = SA * rv2 + cn2 * __low2float(uh);
    SB = SB * rv2 + cn2 * __high2float(uh);
  };

  auto group = [&](int s4, int slotbase, bool emit) __attribute__((always_inline)) {
    uint2 xa = *(const uint2*)&xf_lds[crow * XPAD + s4];
    uint2 xb = *(const uint2*)&xf_lds[crow * XPAD + s4 + CHC];
    __half2 xA01 = bch(xa.x), xA23 = bch(xa.y);
    __half2 xB01 = bch(xb.x), xB23 = bch(xb.y);
    step(slotbase + 0, __low2float(xA01),  __low2float(xB01),  emit);
    step(slotbase + 1, __high2float(xA01), __high2float(xB01), emit);
    step(slotbase + 2, __low2float(xA23),  __low2float(xB23),  emit);
    step(slotbase + 3, __high2float(xA23), __high2float(xB23), emit);
  };

  // ---- warm phase ----
  for (int s4 = 0; s4 < WU; s4 += 4) group(s4, 0, false);

  // chunk-0 exact start: reset chain A state (true history is empty)
  if (p == 0) {
    SA.x = 0.f; SA.y = 0.f;
    poolP.x = 1.f;
  }

  // ---- emit phase: 8 steps per flush ----
  for (int s8 = WU; s8 < NTW; s8 += 8) {
    group(s8, 0, true);
    group(s8 + 4, 4, true);

    int tg = t0A + (s8 - WU);
    size_t base = (size_t)b * TT + tg;
    if (lid < NBC) {                       // row 0: y_bcn + fb
      size_t ob = base * NBC + lid;
#pragma unroll
      for (int sl = 0; sl < 8; ++sl) {
        yb [ob + sl * NBC]                     = yst[sl].x;
        yb [ob + (size_t)CHC * NBC + sl * NBC] = yst[sl].y;
        fbp[ob + sl * NBC]                     = fst[sl].x;
        fbp[ob + (size_t)CHC * NBC + sl * NBC] = fst[sl].y;
      }
    } else if (lid >= 16 && lid < 16 + NBC) {  // row 1: y_lnr
      size_t ob = base * NBC + (lid - 16);
#pragma unroll
      for (int sl = 0; sl < 8; ++sl) {
        ylp[ob + sl * NBC]                     = yst[sl].x;
        ylp[ob + (size_t)CHC * NBC + sl * NBC] = yst[sl].y;
      }
    }
    if (lid < NAC) {
      size_t oa = base * NAC + lid;
#pragma unroll
      for (int sl = 0; sl < 8; ++sl) {
        __half2 h = bch(acst[sl]);
        acp[oa + sl * NAC]                     = __low2float(h);
        acp[oa + (size_t)CHC * NAC + sl * NAC] = __high2float(h);
      }
    }
  }
}

extern "C" void kernel_launch(void* const* d_in, const int* in_sizes, int n_in,
                              void* d_out, int out_size, void* d_ws, size_t ws_size,
                              hipStream_t stream) {
  (void)in_sizes; (void)n_in; (void)out_size;
  const float* x    = (const float*)d_in[0];
  const float* bck  = (const float*)d_in[1];
  if (ws_size >= XF_BYTES) {
    __half* xfg = (__half*)d_ws;
    conv_kernel<<<dim3(BB * 16), dim3(256), 0, stream>>>(x, bck, xfg);
    bcn_kernel<true><<<dim3(BB * NPAIR), dim3(64), 0, stream>>>(
        x, bck, (const float*)d_in[2], (const float*)d_in[3], (const float*)d_in[4],
        (const float*)d_in[5], (const float*)d_in[6], (const float*)d_in[7],
        (const float*)d_in[8], (const float*)d_in[9], (const float*)d_in[10],
        xfg, (float*)d_out);
  } else {
    bcn_kernel<false><<<dim3(BB * NPAIR), dim3(64), 0, stream>>>(
        x, bck, (const float*)d_in[2], (const float*)d_in[3], (const float*)d_in[4],
        (const float*)d_in[5], (const float*)d_in[6], (const float*)d_in[7],
        (const float*)d_in[8], (const float*)d_in[9], (const float*)d_in[10],
        (const __half*)nullptr, (float*)d_out);
  }
}

// Round 22
// 91.458 us; speedup vs baseline: 1.2233x; 1.1319x over previous
//
#include <hip/hip_runtime.h>
#include <hip/hip_fp16.h>

#define NBC 14
#define NAC 45
#define KF  52
#define RHO 0.05f
#define TT  4096
#define BB  64
#define CHC 64           // outputs per chain
#define WU  44           // warmup steps
#define NPAIR 32         // chunk pairs per batch
#define NTW (WU + CHC)   // 108 steps per chain
#define SPAN (WU + 2*CHC)// 172: xf range covers both chains
#define XPAD 176         // xf row stride (halfs), mult of 4
#define LOG2E 1.44269504f
#define XF_BYTES ((size_t)BB * NBC * TT * 2)

typedef __fp16 v2h __attribute__((ext_vector_type(2)));
typedef float  f2  __attribute__((ext_vector_type(2)));
typedef int    i2v __attribute__((ext_vector_type(2)));

__device__ __forceinline__ v2h bch(unsigned u) { return __builtin_bit_cast(v2h, u); }
__device__ __forceinline__ unsigned bcu(v2h h) { return __builtin_bit_cast(unsigned, h); }
__device__ __forceinline__ v2h pk2(float lo, float hi) {
#if __has_builtin(__builtin_amdgcn_cvt_pkrtz)
  return __builtin_bit_cast(v2h, __builtin_amdgcn_cvt_pkrtz(lo, hi));
#else
  v2h r; r[0] = (__fp16)lo; r[1] = (__fp16)hi; return r;
#endif
}
__device__ __forceinline__ v2h xsum16h(v2h v) {
#if __has_builtin(__builtin_amdgcn_permlane16_swap)
  i2v r = __builtin_amdgcn_permlane16_swap((int)bcu(v), (int)bcu(v), false, false);
  return bch((unsigned)r[0]) + bch((unsigned)r[1]);
#else
  return v + bch((unsigned)__builtin_amdgcn_ds_swizzle((int)bcu(v), (16 << 10) | 0x1f));
#endif
}
__device__ __forceinline__ v2h xsum32h(v2h v) {
#if __has_builtin(__builtin_amdgcn_permlane32_swap)
  i2v r = __builtin_amdgcn_permlane32_swap((int)bcu(v), (int)bcu(v), false, false);
  return bch((unsigned)r[0]) + bch((unsigned)r[1]);
#else
  return v + bch((unsigned)__shfl_xor((int)bcu(v), 32));
#endif
}
__device__ __forceinline__ float exp2_f(float x) {
#if __has_builtin(__builtin_amdgcn_exp2f)
  return __builtin_amdgcn_exp2f(x);
#else
  return exp2f(x);
#endif
}

// ---------------- conv pre-pass: xf[b][c][t] for all t ----------------
__global__ __launch_bounds__(256)
void conv_kernel(const float* __restrict__ x, const float* __restrict__ bck,
                 __half* __restrict__ xfg) {
  __shared__ float xs[256 + KF];        // tile + halo
  const int tid  = threadIdx.x;
  const int b    = blockIdx.x >> 4;     // 16 tiles of 256
  const int t0   = (blockIdx.x & 15) << 8;
  for (int i = tid; i < 256 + KF - 1; i += 256) {
    int gt = t0 - (KF - 1) + i;
    xs[i] = (gt >= 0) ? x[b * TT + gt] : 0.f;
  }
  __syncthreads();
  float acc[NBC];
#pragma unroll
  for (int c = 0; c < NBC; ++c) acc[c] = 0.f;
#pragma unroll 4
  for (int k = 0; k < KF; ++k) {
    float xv = xs[tid + k];
#pragma unroll
    for (int c = 0; c < NBC; ++c) acc[c] = fmaf(bck[c * KF + k], xv, acc[c]);
  }
#pragma unroll
  for (int c = 0; c < NBC; ++c)
    xfg[((size_t)b * NBC + c) * TT + t0 + tid] = __float2half(acc[c]);
}

// LDS pool (bytes):
//  [0,    4928)  xf fp16 [NBC][XPAD]
//  [4928, 5184)  acr u32 [64]   (entries 45..63 stay zero; 16B aligned)
//  [5184, 5248)  relr u32 [16]  (entries 14,15 stay zero)
//  [5248, 6144)  x slice f32 [224]  (in-kernel conv fallback only)
#define POOL_BYTES 6144

template<bool PRECONV>
__global__ __launch_bounds__(64)
void bcn_kernel(const float* __restrict__ x,
                const float* __restrict__ bck,
                const float* __restrict__ lss,
                const float* __restrict__ soff,
                const float* __restrict__ lbaw,
                const float* __restrict__ ltr,
                const float* __restrict__ ltd,
                const float* __restrict__ lass,
                const float* __restrict__ asoff,
                const float* __restrict__ labw,
                const float* __restrict__ oscale,
                const __half* __restrict__ xfg,
                float* __restrict__ out)
{
  __shared__ __align__(16) char pool[POOL_BYTES];
  __half*   xf_lds = (__half*)pool;                    // [NBC][XPAD]
  unsigned* acr    = (unsigned*)(pool + 4928);         // [64]
  unsigned* relr   = (unsigned*)(pool + 5184);         // [16]
  float*    x_lds  = (float*)(pool + 5248);            // conv fallback only

  const int lid   = threadIdx.x;
  const int c16   = lid & 15;
  const int q     = lid >> 4;
  const float rowm = (q & 1) ? 0.f : 1.f;   // rows 0,2: BCN; rows 1,3: LNR
  const int blk   = blockIdx.x;
  const int b     = blk >> 5;            // batch
  const int p     = blk & 31;            // chunk pair
  const int t0A   = p * (2 * CHC);
  const int t_begin = t0A - WU;

  if constexpr (PRECONV) {
    // ---- copy precomputed xf slice into LDS (clamp t<0; p==0 only) ----
    const __half* src = xfg + (size_t)b * NBC * TT;
    if (p == 0) {
      for (int e = lid; e < NBC * SPAN; e += 64) {
        int c = e / SPAN, i = e - c * SPAN;
        int gt = t_begin + i; if (gt < 0) gt = 0;   // chain-A warm garbage, reset later
        xf_lds[c * XPAD + i] = src[(size_t)c * TT + gt];
      }
    } else {
      for (int c = 0; c < NBC; ++c) {
        if (lid < SPAN / 4) {
          uint2 v = *(const uint2*)(src + (size_t)c * TT + t_begin + 4 * lid);
          *(uint2*)&xf_lds[c * XPAD + 4 * lid] = v;
        }
      }
    }
  } else {
    // ---- in-kernel conv (fallback when d_ws too small) ----
    for (int i = lid; i < SPAN + KF - 1; i += 64) {
      int gt = t_begin - (KF - 1) + i;
      x_lds[i] = (gt >= 0) ? x[b * TT + gt] : 0.f;
    }
    __syncthreads();
    for (int ib = 0; ib < 3; ++ib) {
      int tau = lid + (ib << 6);
      if (tau < SPAN) {
        float acc[NBC];
#pragma unroll
        for (int c = 0; c < NBC; ++c) acc[c] = 0.f;
#pragma unroll 4
        for (int k = 0; k < KF; ++k) {
          float xv = x_lds[tau + k];
#pragma unroll
          for (int c = 0; c < NBC; ++c) acc[c] = fmaf(bck[c * KF + k], xv, acc[c]);
        }
#pragma unroll
        for (int c = 0; c < NBC; ++c) xf_lds[c * XPAD + tau] = __float2half(acc[c]);
      }
    }
    __syncthreads();
  }

  // ---- zero acr + relr ----
  if (lid < 64) acr[lid] = 0u;
  if (lid < 16) relr[lid] = 0u;

  // ---- per-lane parameters ----
  float slope2 = 0.f, soff2 = 0.f, osc_c = 0.f;
  f2 poolP; poolP.x = 1.f; poolP.y = 1.f;
  f2 SA; SA.x = 0.f; SA.y = 0.f;      // (S1,S2) chain A — infinite-history states
  f2 SB; SB.x = 0.f; SB.y = 0.f;
  f2 rv2, cn2; rv2.x = rv2.y = cn2.x = cn2.y = 0.f;
  float Adrv2 = 0.f, Boff2 = 0.f;
  v2h wfbh[16];
  v2h wuh[NBC];
  f2 yst[4], fst[4];
  unsigned acst[4];

#pragma unroll
  for (int j = 0; j < 16; ++j) wfbh[j] = pk2(0.f, 0.f);
#pragma unroll
  for (int c = 0; c < NBC; ++c) wuh[c] = pk2(0.f, 0.f);

  if (c16 < NBC) {
    float sl = expf(lss[c16]);
    slope2 = sl * LOG2E;
    soff2  = soff[c16] * sl * LOG2E;
    osc_c  = oscale[c16];
#pragma unroll
    for (int j = 0; j < 16; ++j) {
      int a = 16 * q + j;
      if (a < NAC) { float w = -expf(labw[c16 * NAC + a]); wfbh[j] = pk2(w, w); }
    }
  }
  if (lid < NAC) {
    float tr = expf(ltr[lid]);
    float td = expf(ltd[lid]);
    float a1 = 1.f / td;
    float gg = (td + tr) / (td * tr);
    rv2.x = expf(-a1 * 0.015625f);  rv2.y = expf(-gg * 0.015625f);
    cn2.x = expf(-a1 * 0.003125f);  cn2.y = expf(-gg * 0.003125f);
    float nrm = 0.f;
    for (int k = 0; k < KF; ++k) {
      float kt = 0.8f - (float)k * 0.015625f;
      float d = expf(-a1 * kt) - expf(-gg * kt);
      nrm = fmaf(d, d, nrm);
    }
    float inorm  = 1.f / sqrtf(nrm);
    float aslope = expf(lass[lid]);
    Adrv2 = aslope * inorm * LOG2E;
    Boff2 = aslope * asoff[lid] * LOG2E;
#pragma unroll
    for (int c = 0; c < NBC; ++c) {
      float w = expf(lbaw[lid * NBC + c]);
      wuh[c] = pk2(w, w);
    }
  }

  float* yb  = out;
  float* fbp = out + (size_t)BB * TT * NBC;
  float* acp = out + 2 * (size_t)BB * TT * NBC;
  float* ylp = out + 2 * (size_t)BB * TT * NBC + (size_t)BB * TT * NAC;

  __syncthreads();

  auto step = [&](int slot4, float xfA, float xfB, bool emit)
      __attribute__((always_inline)) {
    float mzA = fmaf(-Adrv2, SA.x - SA.y, Boff2);
    float mzB = fmaf(-Adrv2, SB.x - SB.y, Boff2);
    float acA = __fdividef(1.f, 1.f + exp2_f(mzA));
    float acB = __fdividef(1.f, 1.f + exp2_f(mzB));
    if (lid < NAC) acr[lid] = bcu(pk2(acA, acB));

    const uint4* ab = (const uint4*)(acr + (q << 4));
    uint4 A0 = ab[0], A1 = ab[1], A2 = ab[2], A3 = ab[3];
    v2h g0 = wfbh[0] * bch(A0.x);
    v2h g1 = wfbh[1] * bch(A0.y);
    g0 += wfbh[2]  * bch(A0.z);  g1 += wfbh[3]  * bch(A0.w);
    g0 += wfbh[4]  * bch(A1.x);  g1 += wfbh[5]  * bch(A1.y);
    g0 += wfbh[6]  * bch(A1.z);  g1 += wfbh[7]  * bch(A1.w);
    g0 += wfbh[8]  * bch(A2.x);  g1 += wfbh[9]  * bch(A2.y);
    g0 += wfbh[10] * bch(A2.z);  g1 += wfbh[11] * bch(A2.w);
    g0 += wfbh[12] * bch(A3.x);  g1 += wfbh[13] * bch(A3.y);
    g0 += wfbh[14] * bch(A3.z);  g1 += wfbh[15] * bch(A3.w);
    v2h gs = xsum32h(xsum16h(g0 + g1));
    float fbA = (float)gs[0], fbB = (float)gs[1];

    float mA = fmaf(-slope2, fmaf(rowm, fbA, xfA), soff2);
    float mB = fmaf(-slope2, fmaf(rowm, fbB, xfB), soff2);
    f2 pv;
    pv.x = __fdividef(1.f, 1.f + exp2_f(mA));
    pv.y = __fdividef(1.f, 1.f + exp2_f(mB));
    f2 p2 = poolP * (1.f - RHO) + RHO;
    f2 relP = pv * p2;
    poolP = p2 - relP;
    if (lid < NBC) relr[lid] = bcu(pk2(relP.x, relP.y));
    if (emit) {
      yst[slot4] = relP * osc_c;
      f2 t; t.x = fbA; t.y = fbB; fst[slot4] = t;
      acst[slot4] = bcu(pk2(acA, acB));
    }

    const uint4* rb = (const uint4*)relr;
    uint4 R0 = rb[0], R1 = rb[1], R2 = rb[2], R3 = rb[3];
    v2h h0 = wuh[0] * bch(R0.x);
    v2h h1 = wuh[1] * bch(R0.y);
    h0 += wuh[2]  * bch(R0.z);  h1 += wuh[3]  * bch(R0.w);
    h0 += wuh[4]  * bch(R1.x);  h1 += wuh[5]  * bch(R1.y);
    h0 += wuh[6]  * bch(R1.z);  h1 += wuh[7]  * bch(R1.w);
    h0 += wuh[8]  * bch(R2.x);  h1 += wuh[9]  * bch(R2.y);
    h0 += wuh[10] * bch(R2.z);  h1 += wuh[11] * bch(R2.w);
    h0 += wuh[12] * bch(R3.x);  h1 += wuh[13] * bch(R3.y);
    v2h uh = h0 + h1;
    // infinite-history exponential states (tail beyond kt=0.8 is <=3e-4 in ac)
    SA = SA * rv2 + cn2 * (float)uh[0];
    SB = SB * rv2 + cn2 * (float)uh[1];
  };

  auto group = [&](int s4, bool emit) __attribute__((always_inline)) {
    uint2 xa = *(const uint2*)&xf_lds[c16 * XPAD + s4];
    uint2 xb = *(const uint2*)&xf_lds[c16 * XPAD + s4 + CHC];
    v2h xA01 = bch(xa.x), xA23 = bch(xa.y);
    v2h xB01 = bch(xb.x), xB23 = bch(xb.y);
    step(0, (float)xA01[0], (float)xB01[0], emit);
    step(1, (float)xA01[1], (float)xB01[1], emit);
    step(2, (float)xA23[0], (float)xB23[0], emit);
    step(3, (float)xA23[1], (float)xB23[1], emit);
  };

  // ---- warm phase ----
  for (int s4 = 0; s4 < WU; s4 += 4) group(s4, false);

  // chunk-0 exact start: reset chain A state (true history is empty)
  if (p == 0) {
    SA.x = 0.f; SA.y = 0.f;
    poolP.x = 1.f;
  }

  // ---- emit phase ----
  for (int s4 = WU; s4 < NTW; s4 += 4) {
    group(s4, true);

    int tgA = t0A + (s4 - WU);
    size_t baseA = (size_t)b * TT + tgA;
    if (lid < NBC) {                       // row 0: y_bcn + fb
      size_t ob = baseA * NBC + lid;
#pragma unroll
      for (int sl = 0; sl < 4; ++sl) {
        yb [ob + sl * NBC]                     = yst[sl].x;
        yb [ob + (size_t)CHC * NBC + sl * NBC] = yst[sl].y;
        fbp[ob + sl * NBC]                     = fst[sl].x;
        fbp[ob + (size_t)CHC * NBC + sl * NBC] = fst[sl].y;
      }
    } else if (lid >= 16 && lid < 16 + NBC) {  // row 1: y_lnr
      size_t ob = baseA * NBC + (lid - 16);
#pragma unroll
      for (int sl = 0; sl < 4; ++sl) {
        ylp[ob + sl * NBC]                     = yst[sl].x;
        ylp[ob + (size_t)CHC * NBC + sl * NBC] = yst[sl].y;
      }
    }
    if (lid < NAC) {
      size_t oa = baseA * NAC + lid;
#pragma unroll
      for (int sl = 0; sl < 4; ++sl) {
        v2h h = bch(acst[sl]);
        acp[oa + sl * NAC]                     = (float)h[0];
        acp[oa + (size_t)CHC * NAC + sl * NAC] = (float)h[1];
      }
    }
  }
}

extern "C" void kernel_launch(void* const* d_in, const int* in_sizes, int n_in,
                              void* d_out, int out_size, void* d_ws, size_t ws_size,
                              hipStream_t stream) {
  (void)in_sizes; (void)n_in; (void)out_size;
  const float* x    = (const float*)d_in[0];
  const float* bck  = (const float*)d_in[1];
  if (ws_size >= XF_BYTES) {
    __half* xfg = (__half*)d_ws;
    conv_kernel<<<dim3(BB * 16), dim3(256), 0, stream>>>(x, bck, xfg);
    bcn_kernel<true><<<dim3(BB * NPAIR), dim3(64), 0, stream>>>(
        x, bck, (const float*)d_in[2], (const float*)d_in[3], (const float*)d_in[4],
        (const float*)d_in[5], (const float*)d_in[6], (const float*)d_in[7],
        (const float*)d_in[8], (const float*)d_in[9], (const float*)d_in[10],
        xfg, (float*)d_out);
  } else {
    bcn_kernel<false><<<dim3(BB * NPAIR), dim3(64), 0, stream>>>(
        x, bck, (const float*)d_in[2], (const float*)d_in[3], (const float*)d_in[4],
        (const float*)d_in[5], (const float*)d_in[6], (const float*)d_in[7],
        (const float*)d_in[8], (const float*)d_in[9], (const float*)d_in[10],
        (const __half*)nullptr, (float*)d_out);
  }
}